// Round 14
// baseline (610.728 us; speedup 1.0000x reference)
//
#include <hip/hip_runtime.h>
#include <cstdint>
#include <cstddef>

#define NNODES 50000
#define NEDGE0 400000
#define NETOT  450000
#define NGRAPH 1024
#define CH     312
#define HC     624
#define MP     50048     // NNODES padded to 128
#define KPA    320       // CH padded to 64 (slot width, shorts)
#define AST    640       // activation row stride = 2 slots
#define KP0    128       // 78 padded (layer-0 input)
#define GW1    1024      // head fc1 width

typedef __attribute__((ext_vector_type(4))) float f32x4;
typedef __attribute__((ext_vector_type(8))) short s16x8;

__device__ __forceinline__ unsigned short f2bf(float x) {
  union { float f; unsigned u; } v; v.f = x;
  unsigned r = v.u + 0x7fffu + ((v.u >> 16) & 1u);   // RNE
  return (unsigned short)(r >> 16);
}
__device__ __forceinline__ float bf2f(unsigned short u) {
  union { unsigned u; float f; } v; v.u = ((unsigned)u) << 16;
  return v.f;
}
__device__ __forceinline__ void gl_lds16(const unsigned short* g, unsigned short* l) {
  __builtin_amdgcn_global_load_lds(
      (const __attribute__((address_space(1))) unsigned int*)g,
      (__attribute__((address_space(3))) unsigned int*)l, 16, 0, 0);
}

// ============ fused pre-pass (segment-dispatched mega-kernel) ============
__device__ __forceinline__ void combcast_d(int i, const float* __restrict__ W,
                                           unsigned short* __restrict__ out,
                                           int K, int KX) {
  int W2 = 2 * KX;
  if (i >= 384 * W2) return;
  int n = i / W2, k = i - n * W2;
  float v = 0.f;
  if (n < CH) {
    int hd = (k >= KX) ? 1 : 0;
    int kk = hd ? k - KX : k;
    if (kk < K) v = 0.5f * W[(size_t)kk * HC + hd * CH + n];
  }
  out[i] = f2bf(v);
}

__device__ __forceinline__ void wafill_d(int i, const float* __restrict__ W,
                                         const float* __restrict__ a_s,
                                         const float* __restrict__ a_d,
                                         float* __restrict__ wa, int K, int KX) {
  if (i >= 4 * KX) return;
  int j = i / KX, k = i - j * KX;
  int hd = j & 1;
  const float* a = (j < 2) ? a_s : a_d;
  float s = 0.f;
  if (k < K)
    for (int c = 0; c < CH; ++c)
      s += W[(size_t)k * HC + hd * CH + c] * a[hd * CH + c];
  wa[j * KX + k] = s;
}

__device__ __forceinline__ void tcast_d(int i, const float* __restrict__ in,
                                        unsigned short* __restrict__ out,
                                        int K, int N, int KP_, int NP_) {
  if (i >= NP_ * KP_) return;
  int n = i / KP_, k = i - n * KP_;
  out[i] = (n < N && k < K) ? f2bf(in[(size_t)k * N + n]) : (unsigned short)0;
}

#define SB0 25024                 // cvt0: MP*KP0/256
#define SB1 (SB0 + 384)           // combcast W0
#define SB2 (SB1 + 960)           // combcast W1
#define SB3 (SB2 + 960)           // combcast W2
#define SB4 (SB3 + 2)             // wafill W0
#define SB5 (SB4 + 5)             // wafill W1
#define SB6 (SB5 + 5)             // wafill W2
#define SB7 (SB6 + 960)           // tcast2 fc12
#define SB8 (SB7 + 5)             // biasprep
#define SB9 (SB8 + 1280)          // tcast g1
#define SB10 (SB9 + 512)          // tcast g2
#define SB11 (SB10 + 5)           // gptr
#define PREPB SB11

__global__ __launch_bounds__(256) void prep_k(
    const float* __restrict__ mol_x, unsigned short* __restrict__ xb0,
    const float* __restrict__ W0, const float* __restrict__ W1,
    const float* __restrict__ W2,
    unsigned short* __restrict__ comb0t, unsigned short* __restrict__ comb1t,
    unsigned short* __restrict__ comb2t,
    const float* __restrict__ as0, const float* __restrict__ ad0,
    const float* __restrict__ as1, const float* __restrict__ ad1,
    const float* __restrict__ as2, const float* __restrict__ ad2,
    float* __restrict__ wa0, float* __restrict__ wa1, float* __restrict__ wa2,
    const float* __restrict__ fc1w, const float* __restrict__ fc2w,
    unsigned short* __restrict__ fc12t,
    const float* __restrict__ b0_, const float* __restrict__ b1_,
    const float* __restrict__ b2_, const float* __restrict__ fc1b,
    const float* __restrict__ fc2b, const float* __restrict__ mb,
    float* __restrict__ bp0, float* __restrict__ bp1, float* __restrict__ bp2,
    float* __restrict__ gb,
    const float* __restrict__ g1w, unsigned short* __restrict__ g1t,
    const float* __restrict__ g2w, unsigned short* __restrict__ g2t,
    const int* __restrict__ batch, int* __restrict__ gptr)
{
  int b = blockIdx.x, t = threadIdx.x;
  if (b < SB0) {                       // cvt0: mol_x -> xb0 [MP][KP0]
    int i = b * 256 + t;
    int n = i >> 7, c = i & 127;
    xb0[i] = (n < NNODES && c < 78) ? f2bf(mol_x[(size_t)n * 78 + c])
                                    : (unsigned short)0;
  } else if (b < SB1) { combcast_d((b - SB0) * 256 + t, W0, comb0t, 78, KP0); }
  else if (b < SB2) { combcast_d((b - SB1) * 256 + t, W1, comb1t, CH, KPA); }
  else if (b < SB3) { combcast_d((b - SB2) * 256 + t, W2, comb2t, CH, KPA); }
  else if (b < SB4) { wafill_d((b - SB3) * 256 + t, W0, as0, ad0, wa0, 78, KP0); }
  else if (b < SB5) { wafill_d((b - SB4) * 256 + t, W1, as1, ad1, wa1, CH, KPA); }
  else if (b < SB6) { wafill_d((b - SB5) * 256 + t, W2, as2, ad2, wa2, CH, KPA); }
  else if (b < SB7) {                  // tcast2: [fc1;fc2] -> fc12t[384][640]
    int i = (b - SB6) * 256 + t;
    if (i < 384 * AST) {
      int n = i / AST, k = i - n * AST;
      float v = 0.f;
      if (n < CH) {
        if (k < CH) v = fc1w[(size_t)k * CH + n];
        else if (k >= KPA && k - KPA < CH) v = fc2w[(size_t)(k - KPA) * CH + n];
      }
      fc12t[i] = f2bf(v);
    }
  } else if (b < SB8) {                // biasprep
    int i = (b - SB7) * 256 + t;
    if (i < 4 * KPA) {
      int seg = i / KPA, c = i - seg * KPA;
      bool in = c < CH;
      if (seg == 0)      bp0[c] = in ? b0_[c] : 0.f;
      else if (seg == 1) bp1[c] = in ? b1_[c] : 0.f;
      else if (seg == 2) bp2[c] = in ? b2_[c] : 0.f;
      else               gb[c]  = in ? (fc1b[c] + fc2b[c] + mb[c]) : 0.f;
    }
  } else if (b < SB9) { tcast_d((b - SB8) * 256 + t, g1w, g1t, CH, GW1, KPA, GW1); }
  else if (b < SB10) { tcast_d((b - SB9) * 256 + t, g2w, g2t, GW1, 128, GW1, 128); }
  else {                               // gptr: binary search per graph
    int g = (b - SB10) * 256 + t;
    if (g > NGRAPH) return;
    int lo = 0, hi = NNODES;
    while (lo < hi) { int mid = (lo + hi) >> 1; if (batch[mid] < g) lo = mid + 1; else hi = mid; }
    gptr[g] = lo;
  }
}

// ============ MFMA GEMM with fused epilogues ============
// BM=128 BN=128 BK=64, 4 waves (2x2, 64x64 each), 64KB LDS -> 2 blocks/CU,
// depth-2 counted-vmcnt pipeline (vmcnt(8) steady), raw barriers, XCD swizzle.
// Epilogue: two 64-col half-passes through LDS f32 [128][68] -> coalesced stores.
__global__ __launch_bounds__(256) void gemm_bb(
    const unsigned short* __restrict__ A, int lda,
    const unsigned short* __restrict__ Bt,
    unsigned short* __restrict__ Cb, float* __restrict__ Cf,
    const float* __restrict__ bias,
    const unsigned short* __restrict__ Xg, const unsigned short* __restrict__ Hg,
    int M, int N, int KP_, int ldc, int act, int gx)
{
  const int nwg = gridDim.x, orig = blockIdx.x;
  const int q = nwg >> 3, r = nwg & 7;
  const int xcd = orig & 7, loc = orig >> 3;
  const int swz = (xcd < r ? xcd * (q + 1) : r * (q + 1) + (xcd - r) * q) + loc;
  const int bn = (swz % gx) * 128, bm = (swz / gx) * 128;

  __shared__ __align__(16) char smem[65536];
  unsigned short* As = (unsigned short*)smem;            // [2][128*64]
  unsigned short* Bs = (unsigned short*)(smem + 32768);  // [2][128*64]
  const int tid = threadIdx.x, lane = tid & 63, w = tid >> 6;
  const int rr = lane >> 3;
  const int cc8 = (lane & 7) ^ rr;

  const int nkt = KP_ >> 6;

  auto stage = [&](int b, int kt) {
    #pragma unroll
    for (int i = 0; i < 4; ++i) {
      int R = w * 32 + i * 8;
      gl_lds16(A + (size_t)(bm + R + rr) * lda + kt * 64 + cc8 * 8,
               As + b * 8192 + R * 64);
      gl_lds16(Bt + (size_t)(bn + R + rr) * KP_ + kt * 64 + cc8 * 8,
               Bs + b * 8192 + R * 64);
    }
  };

  const int wr = w >> 1, wc = w & 1;
  const int r16 = lane & 15, g4 = lane >> 4;
  f32x4 zf = {0.f, 0.f, 0.f, 0.f};
  f32x4 acc[4][4];
  #pragma unroll
  for (int m = 0; m < 4; ++m)
    #pragma unroll
    for (int n = 0; n < 4; ++n) acc[m][n] = zf;

  stage(0, 0);
  stage(1, 1);
  int buf = 0;
  for (int kt = 0; kt < nkt; ++kt) {
    if (kt == nkt - 1) asm volatile("s_waitcnt vmcnt(0)" ::: "memory");
    else               asm volatile("s_waitcnt vmcnt(8)" ::: "memory");
    __builtin_amdgcn_s_barrier();
    #pragma unroll
    for (int k2 = 0; k2 < 2; ++k2) {
      s16x8 bfr[4], afr[4];
      #pragma unroll
      for (int n = 0; n < 4; ++n) {
        int rB = wc * 64 + n * 16 + r16;
        int ch = (k2 * 4 + g4) ^ (rB & 7);
        bfr[n] = *(const s16x8*)&Bs[buf * 8192 + rB * 64 + ch * 8];
      }
      #pragma unroll
      for (int m = 0; m < 4; ++m) {
        int rA = wr * 64 + m * 16 + r16;
        int ch = (k2 * 4 + g4) ^ (rA & 7);
        afr[m] = *(const s16x8*)&As[buf * 8192 + rA * 64 + ch * 8];
      }
      __builtin_amdgcn_s_setprio(1);
      #pragma unroll
      for (int m = 0; m < 4; ++m)
        #pragma unroll
        for (int n = 0; n < 4; ++n)
          acc[m][n] = __builtin_amdgcn_mfma_f32_16x16x32_bf16(afr[m], bfr[n],
                                                              acc[m][n], 0, 0, 0);
      __builtin_amdgcn_s_setprio(0);
    }
    __builtin_amdgcn_s_barrier();
    if (kt + 2 < nkt) stage(buf, kt + 2);
    buf ^= 1;
  }

  // ---- epilogue: two 64-col half-passes via LDS f32 [128][68] ----
  float* Ct = (float*)smem;
  #pragma unroll
  for (int h = 0; h < 2; ++h) {
    if (wc == h) {
      #pragma unroll
      for (int m = 0; m < 4; ++m) {
        int row0 = wr * 64 + m * 16 + g4 * 4;
        #pragma unroll
        for (int n = 0; n < 4; ++n) {
          int col = n * 16 + r16;
          #pragma unroll
          for (int r2 = 0; r2 < 4; ++r2)
            Ct[(row0 + r2) * 68 + col] = acc[m][n][r2];
        }
      }
    }
    __builtin_amdgcn_s_barrier();

    if (Cf) {
      for (int c = tid; c < 128 * 16; c += 256) {
        int row = c >> 4, c4 = (c & 15) * 4;
        int gm = bm + row, gn = bn + h * 64 + c4;
        if (gm < M && gn < N) {
          f32x4 v;
          #pragma unroll
          for (int rj = 0; rj < 4; ++rj) {
            float x = Ct[row * 68 + c4 + rj] + bias[gn + rj];
            if (act) x = x > 0.f ? x : 0.f;
            v[rj] = x;
          }
          *(f32x4*)(Cf + (size_t)gm * ldc + gn) = v;
        }
      }
    } else {
      for (int c = tid; c < 128 * 8; c += 256) {
        int row = c >> 3, c8 = (c & 7) * 8;
        int gm = bm + row, gn = bn + h * 64 + c8;
        if (gm < M && gn < N) {
          size_t obase = (size_t)gm * ldc + gn;
          s16x8 o;
          if (Xg) {
            s16x8 xv = *(const s16x8*)(Xg + obase);
            s16x8 hv = *(const s16x8*)(Hg + obase);
            #pragma unroll
            for (int rj = 0; rj < 8; ++rj) {
              float v = Ct[row * 68 + c8 + rj] + bias[gn + rj];
              float g = 1.f / (1.f + __expf(-v));
              float x = bf2f((unsigned short)xv[rj]);
              float hh = bf2f((unsigned short)hv[rj]);
              o[rj] = (short)f2bf(g * x + (1.f - g) * hh);
            }
          } else {
            #pragma unroll
            for (int rj = 0; rj < 8; ++rj) {
              float v = Ct[row * 68 + c8 + rj] + bias[gn + rj];
              if (act) v = v > 0.f ? v : 0.f;
              o[rj] = (short)f2bf(v);
            }
          }
          *(s16x8*)(Cb + obase) = o;
        }
      }
    }
    __builtin_amdgcn_s_barrier();
  }
}

// ============ CSR build ============
__global__ void hist_k(const int* __restrict__ ei, int* __restrict__ cnt) {
  int e = blockIdx.x * blockDim.x + threadIdx.x;
  if (e >= NETOT) return;
  int d = (e < NEDGE0) ? ei[NEDGE0 + e] : e - NEDGE0;
  atomicAdd(&cnt[d], 1);
}

__global__ __launch_bounds__(1024) void scan_k(const int* __restrict__ cnt,
                                               int* __restrict__ rowptr) {
  __shared__ int wsum[16];
  __shared__ int carry_s;
  int t = threadIdx.x, lane = t & 63, wv = t >> 6;
  if (t == 0) carry_s = 0;
  __syncthreads();
  for (int base = 0; base < NNODES; base += 1024) {
    int idx = base + t;
    int v = (idx < NNODES) ? cnt[idx] : 0;
    int s = v;
    #pragma unroll
    for (int off = 1; off < 64; off <<= 1) {
      int x = __shfl_up(s, off);
      if (lane >= off) s += x;
    }
    if (lane == 63) wsum[wv] = s;
    __syncthreads();
    if (wv == 0) {
      int ws = (lane < 16) ? wsum[lane] : 0;
      #pragma unroll
      for (int off = 1; off < 16; off <<= 1) {
        int x = __shfl_up(ws, off);
        if (lane >= off) ws += x;
      }
      if (lane < 16) wsum[lane] = ws;
    }
    __syncthreads();
    int carry = carry_s;
    int woff = wv ? wsum[wv - 1] : 0;
    if (idx < NNODES) rowptr[idx] = carry + woff + s - v;
    __syncthreads();
    if (t == 1023) carry_s = carry + wsum[15];
    __syncthreads();
  }
  if (t == 0) rowptr[NNODES] = carry_s;
}

__global__ void scatter_k(const int* __restrict__ ei, const int* __restrict__ rowptr,
                          int* __restrict__ cur, int* __restrict__ esrc) {
  int e = blockIdx.x * blockDim.x + threadIdx.x;
  if (e >= NETOT) return;
  int s, d;
  if (e < NEDGE0) { s = ei[e]; d = ei[NEDGE0 + e]; }
  else { s = d = e - NEDGE0; }
  int pos = rowptr[d] + atomicAdd(&cur[d], 1);
  esrc[pos] = s;
}

// ============ per-node scores: Sc[n][4] = X[n] · wa[j] ============
template<int NCH>
__global__ __launch_bounds__(256) void scoresX_k(
    const unsigned short* __restrict__ X, int stride,
    const float* __restrict__ wa, float* __restrict__ Sc)
{
  int wid = (blockIdx.x * blockDim.x + threadIdx.x) >> 6;
  int lane = threadIdx.x & 63;
  if (wid >= NNODES) return;
  const int K = NCH * 8;
  float d[4] = {0, 0, 0, 0};
  if (lane < NCH) {
    s16x8 xv = *(const s16x8*)(X + (size_t)wid * stride + lane * 8);
    float xf[8];
    #pragma unroll
    for (int r = 0; r < 8; ++r) xf[r] = bf2f((unsigned short)xv[r]);
    #pragma unroll
    for (int j = 0; j < 4; ++j) {
      const float* wp = wa + j * K + lane * 8;
      float s = 0.f;
      #pragma unroll
      for (int r = 0; r < 8; ++r) s += xf[r] * wp[r];
      d[j] = s;
    }
  }
  #pragma unroll
  for (int off = 32; off; off >>= 1) {
    #pragma unroll
    for (int j = 0; j < 4; ++j) d[j] += __shfl_xor(d[j], off);
  }
  if (lane == 0) {
    f32x4 v = {d[0], d[1], d[2], d[3]};
    *(f32x4*)(Sc + (size_t)wid * 4) = v;
  }
}

// ============ fused edge softmax + X-aggregate (wave per node) ============
template<int NCH>
__global__ __launch_bounds__(256) void msgX_k(
    const int* __restrict__ rowptr, const int* __restrict__ esrc,
    const float* __restrict__ Sc, const unsigned short* __restrict__ X,
    int stride, unsigned short* __restrict__ xagg)
{
  int wid = (blockIdx.x * blockDim.x + threadIdx.x) >> 6;
  int lane = threadIdx.x & 63;
  if (wid >= NNODES) return;
  int e0 = rowptr[wid], e1 = rowptr[wid + 1];
  float sd0 = Sc[(size_t)wid * 4 + 2], sd1 = Sc[(size_t)wid * 4 + 3];

  // ---- phase 1: exact per-head max & sum ----
  float m0 = -1e30f, m1 = -1e30f, z0 = 0.f, z1 = 0.f;
  for (int base = e0; base < e1; base += 64) {
    int cnt = e1 - base; if (cnt > 64) cnt = 64;
    float a0 = -1e30f, a1 = -1e30f;
    if (lane < cnt) {
      int sl = esrc[base + lane];
      f32x4 sv = *(const f32x4*)(Sc + (size_t)sl * 4);
      a0 = sv[0] + sd0; a0 = a0 > 0.f ? a0 : 0.2f * a0;
      a1 = sv[1] + sd1; a1 = a1 > 0.f ? a1 : 0.2f * a1;
    }
    float cm0 = a0, cm1 = a1;
    #pragma unroll
    for (int off = 32; off; off >>= 1) {
      cm0 = fmaxf(cm0, __shfl_xor(cm0, off));
      cm1 = fmaxf(cm1, __shfl_xor(cm1, off));
    }
    float nm0 = fmaxf(m0, cm0), nm1 = fmaxf(m1, cm1);
    z0 *= __expf(m0 - nm0); z1 *= __expf(m1 - nm1);
    m0 = nm0; m1 = nm1;
    float w0 = (lane < cnt) ? __expf(a0 - m0) : 0.f;
    float w1 = (lane < cnt) ? __expf(a1 - m1) : 0.f;
    #pragma unroll
    for (int off = 32; off; off >>= 1) {
      w0 += __shfl_xor(w0, off);
      w1 += __shfl_xor(w1, off);
    }
    z0 += w0; z1 += w1;
  }
  float i0 = 1.f / (z0 + 1e-16f), i1 = 1.f / (z1 + 1e-16f);

  float a0h[8] = {0,0,0,0,0,0,0,0};
  float a1h[8] = {0,0,0,0,0,0,0,0};

  // ---- phase 2: final coefs + weighted X gather ----
  for (int base = e0; base < e1; base += 64) {
    int cnt = e1 - base; if (cnt > 64) cnt = 64;
    int sl = 0;
    float c0 = 0.f, c1 = 0.f;
    if (lane < cnt) {
      sl = esrc[base + lane];
      f32x4 sv = *(const f32x4*)(Sc + (size_t)sl * 4);
      float a0 = sv[0] + sd0; a0 = a0 > 0.f ? a0 : 0.2f * a0;
      float a1 = sv[1] + sd1; a1 = a1 > 0.f ? a1 : 0.2f * a1;
      c0 = __expf(a0 - m0) * i0;
      c1 = __expf(a1 - m1) * i1;
    }
    if (NCH == 40) {
      for (int e = 0; e < cnt; ++e) {
        int   s  = __shfl(sl, e);
        float w0 = __shfl(c0, e), w1 = __shfl(c1, e);
        if (lane < NCH) {
          s16x8 xv = *(const s16x8*)(X + (size_t)s * stride + lane * 8);
          #pragma unroll
          for (int r = 0; r < 8; ++r) {
            float xf = bf2f((unsigned short)xv[r]);
            a0h[r] += w0 * xf;
            a1h[r] += w1 * xf;
          }
        }
      }
    } else {  // NCH == 16: 4 edges per step, lane = (edge-sub << 4) | chunk
      for (int e = 0; e < cnt; e += 4) {
        int ee = e + (lane >> 4);
        bool on = ee < cnt;
        int   s  = __shfl(sl, on ? ee : e);
        float w0 = __shfl(c0, on ? ee : e), w1 = __shfl(c1, on ? ee : e);
        if (on) {
          s16x8 xv = *(const s16x8*)(X + (size_t)s * stride + (lane & 15) * 8);
          #pragma unroll
          for (int r = 0; r < 8; ++r) {
            float xf = bf2f((unsigned short)xv[r]);
            a0h[r] += w0 * xf;
            a1h[r] += w1 * xf;
          }
        }
      }
    }
  }

  if (NCH == 16) {
    #pragma unroll
    for (int r = 0; r < 8; ++r) {
      a0h[r] += __shfl_xor(a0h[r], 16); a0h[r] += __shfl_xor(a0h[r], 32);
      a1h[r] += __shfl_xor(a1h[r], 16); a1h[r] += __shfl_xor(a1h[r], 32);
    }
  }
  if (lane < NCH) {
    s16x8 o0, o1;
    #pragma unroll
    for (int r = 0; r < 8; ++r) {
      o0[r] = (short)f2bf(a0h[r]);
      o1[r] = (short)f2bf(a1h[r]);
    }
    unsigned short* op = xagg + (size_t)wid * (2 * NCH * 8);
    *(s16x8*)(op + lane * 8) = o0;
    *(s16x8*)(op + NCH * 8 + lane * 8) = o1;
  }
}

// ============ pooling ============
__global__ __launch_bounds__(256) void pool_k(const unsigned short* __restrict__ hs,
                                              const int* __restrict__ gptr,
                                              unsigned short* __restrict__ pooled) {
  int g = blockIdx.x;
  int n0 = gptr[g], n1 = gptr[g + 1];
  float inv = (n1 > n0) ? 1.f / (float)(n1 - n0) : 0.f;
  for (int c = threadIdx.x; c < KPA; c += 256) {
    float s = 0.f;
    if (c < CH)
      for (int n = n0; n < n1; ++n) s += bf2f(hs[(size_t)n * AST + c]);
    pooled[(size_t)g * KPA + c] = f2bf(s * inv);
  }
}

extern "C" void kernel_launch(void* const* d_in, const int* in_sizes, int n_in,
                              void* d_out, int out_size, void* d_ws, size_t ws_size,
                              hipStream_t stream)
{
  const float* mol_x = (const float*)d_in[0];
  const int*   ei    = (const int*)d_in[1];
  const int*   batch = (const int*)d_in[2];
  const float* W0  = (const float*)d_in[3];
  const float* as0 = (const float*)d_in[4];
  const float* ad0 = (const float*)d_in[5];
  const float* b0  = (const float*)d_in[6];
  const float* W1  = (const float*)d_in[7];
  const float* as1 = (const float*)d_in[8];
  const float* ad1 = (const float*)d_in[9];
  const float* b1  = (const float*)d_in[10];
  const float* W2  = (const float*)d_in[11];
  const float* as2 = (const float*)d_in[12];
  const float* ad2 = (const float*)d_in[13];
  const float* b2  = (const float*)d_in[14];
  const float* fc1w = (const float*)d_in[15];
  const float* fc1b = (const float*)d_in[16];
  const float* fc2w = (const float*)d_in[17];
  const float* fc2b = (const float*)d_in[18];
  const float* mbias = (const float*)d_in[19];
  const float* g1w = (const float*)d_in[20];
  const float* g1b = (const float*)d_in[21];
  const float* g2w = (const float*)d_in[22];
  const float* g2b = (const float*)d_in[23];
  float* out = (float*)d_out;

  char* ws = (char*)d_ws;
  size_t off = 0;
  auto alloc = [&](size_t b) { size_t r = off; off += (b + 255) & ~(size_t)255; return r; };
  unsigned short* xagg = (unsigned short*)(ws + alloc((size_t)MP * AST * 2));
  unsigned short* actA = (unsigned short*)(ws + alloc((size_t)MP * AST * 2));
  unsigned short* actB = (unsigned short*)(ws + alloc((size_t)MP * AST * 2));
  unsigned short* xb0  = (unsigned short*)(ws + alloc((size_t)MP * KP0 * 2));
  float* Sc     = (float*)(ws + alloc((size_t)MP * 4 * 4));
  int*   cnt    = (int*)(ws + alloc((size_t)2 * NNODES * 4));
  int*   cnt2   = cnt + NNODES;
  int*   rowptr = (int*)(ws + alloc((size_t)(NNODES + 1) * 4));
  int*   esrc   = (int*)(ws + alloc((size_t)NETOT * 4));
  int*   gptr   = (int*)(ws + alloc((size_t)(NGRAPH + 1) * 4));
  float* gbias  = (float*)(ws + alloc((size_t)KPA * 4));
  float* bp0    = (float*)(ws + alloc((size_t)KPA * 4));
  float* bp1    = (float*)(ws + alloc((size_t)KPA * 4));
  float* bp2    = (float*)(ws + alloc((size_t)KPA * 4));
  float* wa0    = (float*)(ws + alloc((size_t)4 * KP0 * 4));
  float* wa1    = (float*)(ws + alloc((size_t)4 * KPA * 4));
  float* wa2    = (float*)(ws + alloc((size_t)4 * KPA * 4));
  unsigned short* pooled_b = (unsigned short*)(ws + alloc((size_t)NGRAPH * KPA * 2));
  unsigned short* gbuf_b   = (unsigned short*)(ws + alloc((size_t)NGRAPH * GW1 * 2));
  unsigned short* comb0t = (unsigned short*)(ws + alloc((size_t)384 * 256 * 2));
  unsigned short* comb1t = (unsigned short*)(ws + alloc((size_t)384 * AST * 2));
  unsigned short* comb2t = (unsigned short*)(ws + alloc((size_t)384 * AST * 2));
  unsigned short* fc12t  = (unsigned short*)(ws + alloc((size_t)384 * AST * 2));
  unsigned short* g1t    = (unsigned short*)(ws + alloc((size_t)GW1 * KPA * 2));
  unsigned short* g2t    = (unsigned short*)(ws + alloc((size_t)128 * GW1 * 2));

  // ---- pre-pass: CSR chain + fused prep mega-kernel ----
  hipMemsetAsync(cnt, 0, (size_t)2 * NNODES * 4, stream);
  hist_k<<<(NETOT + 255) / 256, 256, 0, stream>>>(ei, cnt);
  scan_k<<<1, 1024, 0, stream>>>(cnt, rowptr);
  scatter_k<<<(NETOT + 255) / 256, 256, 0, stream>>>(ei, rowptr, cnt2, esrc);
  prep_k<<<PREPB, 256, 0, stream>>>(mol_x, xb0, W0, W1, W2, comb0t, comb1t, comb2t,
                                    as0, ad0, as1, ad1, as2, ad2, wa0, wa1, wa2,
                                    fc1w, fc2w, fc12t, b0, b1, b2, fc1b, fc2b, mbias,
                                    bp0, bp1, bp2, gbias, g1w, g1t, g2w, g2t,
                                    batch, gptr);

  auto mgemm = [&](const unsigned short* A, int lda, const unsigned short* Bt,
                   unsigned short* Cb, float* Cf, const float* bias,
                   const unsigned short* Xg, const unsigned short* Hg,
                   int M, int N, int KP_, int ldc, int act) {
    int gx = (N + 127) / 128, gy = (M + 127) / 128;
    hipLaunchKernelGGL(gemm_bb, dim3(gx * gy), dim3(256), 0, stream, A, lda, Bt,
                       Cb, Cf, bias, Xg, Hg, M, N, KP_, ldc, act, gx);
  };

  const int MSGB = (NNODES * 64 + 255) / 256;
  unsigned short* hA = actA + KPA;   // h-slot of actA
  unsigned short* hB = actB + KPA;   // h-slot of actB

  // ---- layer 0: scores -> aggregate X -> combined GEMM -> hA ----
  scoresX_k<16><<<MSGB, 256, 0, stream>>>(xb0, KP0, wa0, Sc);
  msgX_k<16><<<MSGB, 256, 0, stream>>>(rowptr, esrc, Sc, xb0, KP0, xagg);
  mgemm(xagg, 256, comb0t, hA, nullptr, bp0, nullptr, nullptr,
        NNODES, KPA, 256, AST, 1);

  // ---- layer 1 ----
  scoresX_k<40><<<MSGB, 256, 0, stream>>>(hA, AST, wa1, Sc);
  msgX_k<40><<<MSGB, 256, 0, stream>>>(rowptr, esrc, Sc, hA, AST, xagg);
  mgemm(xagg, AST, comb1t, actA, nullptr, bp1, nullptr, nullptr,
        NNODES, KPA, AST, AST, 1);                       // x-slot of actA
  mgemm(actA, AST, fc12t, hB, nullptr, gbias, actA, hA,
        NNODES, KPA, AST, AST, 0);                       // gate -> hB

  // ---- layer 2 ----
  scoresX_k<40><<<MSGB, 256, 0, stream>>>(hB, AST, wa2, Sc);
  msgX_k<40><<<MSGB, 256, 0, stream>>>(rowptr, esrc, Sc, hB, AST, xagg);
  mgemm(xagg, AST, comb2t, actB, nullptr, bp2, nullptr, nullptr,
        NNODES, KPA, AST, AST, 0);                       // x-slot of actB (no relu)
  mgemm(actB, AST, fc12t, hA, nullptr, gbias, actB, hB,
        NNODES, KPA, AST, AST, 0);                       // gate -> hA

  // ---- pool + head ----
  pool_k<<<NGRAPH, 256, 0, stream>>>(hA, gptr, pooled_b);
  mgemm(pooled_b, KPA, g1t, gbuf_b, nullptr, g1b, nullptr, nullptr,
        NGRAPH, GW1, KPA, GW1, 1);
  mgemm(gbuf_b, GW1, g2t, nullptr, out, g2b, nullptr, nullptr,
        NGRAPH, 128, GW1, 128, 0);
}

// Round 15
// 559.448 us; speedup vs baseline: 1.0917x; 1.0917x over previous
//
#include <hip/hip_runtime.h>
#include <cstdint>
#include <cstddef>

#define NNODES 50000
#define NEDGE0 400000
#define NETOT  450000
#define NGRAPH 1024
#define CH     312
#define HC     624
#define MP     50048     // NNODES padded to 128
#define KPA    320       // CH padded to 64 (slot width, shorts)
#define AST    640       // activation row stride = 2 slots
#define KP0    128       // 78 padded (layer-0 input)
#define GW1    1024      // head fc1 width

typedef __attribute__((ext_vector_type(4))) float f32x4;
typedef __attribute__((ext_vector_type(8))) short s16x8;

__device__ __forceinline__ unsigned short f2bf(float x) {
  union { float f; unsigned u; } v; v.f = x;
  unsigned r = v.u + 0x7fffu + ((v.u >> 16) & 1u);   // RNE
  return (unsigned short)(r >> 16);
}
__device__ __forceinline__ float bf2f(unsigned short u) {
  union { unsigned u; float f; } v; v.u = ((unsigned)u) << 16;
  return v.f;
}
__device__ __forceinline__ void gl_lds16(const unsigned short* g, unsigned short* l) {
  __builtin_amdgcn_global_load_lds(
      (const __attribute__((address_space(1))) unsigned int*)g,
      (__attribute__((address_space(3))) unsigned int*)l, 16, 0, 0);
}

// ============ fused pre-pass (segment-dispatched mega-kernel) ============
__device__ __forceinline__ void combcast_d(int i, const float* __restrict__ W,
                                           unsigned short* __restrict__ out,
                                           int K, int KX) {
  int W2 = 2 * KX;
  if (i >= 384 * W2) return;
  int n = i / W2, k = i - n * W2;
  float v = 0.f;
  if (n < CH) {
    int hd = (k >= KX) ? 1 : 0;
    int kk = hd ? k - KX : k;
    if (kk < K) v = 0.5f * W[(size_t)kk * HC + hd * CH + n];
  }
  out[i] = f2bf(v);
}

__device__ __forceinline__ void wafill_d(int i, const float* __restrict__ W,
                                         const float* __restrict__ a_s,
                                         const float* __restrict__ a_d,
                                         float* __restrict__ wa, int K, int KX) {
  if (i >= 4 * KX) return;
  int j = i / KX, k = i - j * KX;
  int hd = j & 1;
  const float* a = (j < 2) ? a_s : a_d;
  float s = 0.f;
  if (k < K)
    for (int c = 0; c < CH; ++c)
      s += W[(size_t)k * HC + hd * CH + c] * a[hd * CH + c];
  wa[j * KX + k] = s;
}

__device__ __forceinline__ void tcast_d(int i, const float* __restrict__ in,
                                        unsigned short* __restrict__ out,
                                        int K, int N, int KP_, int NP_) {
  if (i >= NP_ * KP_) return;
  int n = i / KP_, k = i - n * KP_;
  out[i] = (n < N && k < K) ? f2bf(in[(size_t)k * N + n]) : (unsigned short)0;
}

#define SB0 25024                 // cvt0: MP*KP0/256
#define SB1 (SB0 + 384)           // combcast W0
#define SB2 (SB1 + 960)           // combcast W1
#define SB3 (SB2 + 960)           // combcast W2
#define SB4 (SB3 + 2)             // wafill W0
#define SB5 (SB4 + 5)             // wafill W1
#define SB6 (SB5 + 5)             // wafill W2
#define SB7 (SB6 + 960)           // tcast2 fc12
#define SB8 (SB7 + 5)             // biasprep
#define SB9 (SB8 + 1280)          // tcast g1
#define SB10 (SB9 + 512)          // tcast g2
#define SB11 (SB10 + 5)           // gptr
#define PREPB SB11

__global__ __launch_bounds__(256) void prep_k(
    const float* __restrict__ mol_x, unsigned short* __restrict__ xb0,
    const float* __restrict__ W0, const float* __restrict__ W1,
    const float* __restrict__ W2,
    unsigned short* __restrict__ comb0t, unsigned short* __restrict__ comb1t,
    unsigned short* __restrict__ comb2t,
    const float* __restrict__ as0, const float* __restrict__ ad0,
    const float* __restrict__ as1, const float* __restrict__ ad1,
    const float* __restrict__ as2, const float* __restrict__ ad2,
    float* __restrict__ wa0, float* __restrict__ wa1, float* __restrict__ wa2,
    const float* __restrict__ fc1w, const float* __restrict__ fc2w,
    unsigned short* __restrict__ fc12t,
    const float* __restrict__ b0_, const float* __restrict__ b1_,
    const float* __restrict__ b2_, const float* __restrict__ fc1b,
    const float* __restrict__ fc2b, const float* __restrict__ mb,
    float* __restrict__ bp0, float* __restrict__ bp1, float* __restrict__ bp2,
    float* __restrict__ gb,
    const float* __restrict__ g1w, unsigned short* __restrict__ g1t,
    const float* __restrict__ g2w, unsigned short* __restrict__ g2t,
    const int* __restrict__ batch, int* __restrict__ gptr)
{
  int b = blockIdx.x, t = threadIdx.x;
  if (b < SB0) {                       // cvt0: mol_x -> xb0 [MP][KP0]
    int i = b * 256 + t;
    int n = i >> 7, c = i & 127;
    xb0[i] = (n < NNODES && c < 78) ? f2bf(mol_x[(size_t)n * 78 + c])
                                    : (unsigned short)0;
  } else if (b < SB1) { combcast_d((b - SB0) * 256 + t, W0, comb0t, 78, KP0); }
  else if (b < SB2) { combcast_d((b - SB1) * 256 + t, W1, comb1t, CH, KPA); }
  else if (b < SB3) { combcast_d((b - SB2) * 256 + t, W2, comb2t, CH, KPA); }
  else if (b < SB4) { wafill_d((b - SB3) * 256 + t, W0, as0, ad0, wa0, 78, KP0); }
  else if (b < SB5) { wafill_d((b - SB4) * 256 + t, W1, as1, ad1, wa1, CH, KPA); }
  else if (b < SB6) { wafill_d((b - SB5) * 256 + t, W2, as2, ad2, wa2, CH, KPA); }
  else if (b < SB7) {                  // tcast2: [fc1;fc2] -> fc12t[384][640]
    int i = (b - SB6) * 256 + t;
    if (i < 384 * AST) {
      int n = i / AST, k = i - n * AST;
      float v = 0.f;
      if (n < CH) {
        if (k < CH) v = fc1w[(size_t)k * CH + n];
        else if (k >= KPA && k - KPA < CH) v = fc2w[(size_t)(k - KPA) * CH + n];
      }
      fc12t[i] = f2bf(v);
    }
  } else if (b < SB8) {                // biasprep
    int i = (b - SB7) * 256 + t;
    if (i < 4 * KPA) {
      int seg = i / KPA, c = i - seg * KPA;
      bool in = c < CH;
      if (seg == 0)      bp0[c] = in ? b0_[c] : 0.f;
      else if (seg == 1) bp1[c] = in ? b1_[c] : 0.f;
      else if (seg == 2) bp2[c] = in ? b2_[c] : 0.f;
      else               gb[c]  = in ? (fc1b[c] + fc2b[c] + mb[c]) : 0.f;
    }
  } else if (b < SB9) { tcast_d((b - SB8) * 256 + t, g1w, g1t, CH, GW1, KPA, GW1); }
  else if (b < SB10) { tcast_d((b - SB9) * 256 + t, g2w, g2t, GW1, 128, GW1, 128); }
  else {                               // gptr: binary search per graph
    int g = (b - SB10) * 256 + t;
    if (g > NGRAPH) return;
    int lo = 0, hi = NNODES;
    while (lo < hi) { int mid = (lo + hi) >> 1; if (batch[mid] < g) lo = mid + 1; else hi = mid; }
    gptr[g] = lo;
  }
}

// ============ MFMA GEMM with fused epilogues ============
// BM=128 BN=64 BK=64, 4 waves, 48KB LDS -> 3 blocks/CU, depth-2 counted-vmcnt
// pipeline, raw barriers, XCD-bijective swizzle. LDS-staged coalesced epilogue.
// Optional fused next-layer scores: sj = dot(out bf16 row, wa[j]) via 8-lane
// reduce + atomicAdd into Scout (zeroed beforehand).
__global__ __launch_bounds__(256) void gemm_bb(
    const unsigned short* __restrict__ A, int lda,
    const unsigned short* __restrict__ Bt,
    unsigned short* __restrict__ Cb, float* __restrict__ Cf,
    const float* __restrict__ bias,
    const unsigned short* __restrict__ Xg, const unsigned short* __restrict__ Hg,
    const float* __restrict__ wa, float* __restrict__ Scout,
    int M, int N, int KP_, int ldc, int act, int gx)
{
  const int nwg = gridDim.x, orig = blockIdx.x;
  const int q = nwg >> 3, r = nwg & 7;
  const int xcd = orig & 7, loc = orig >> 3;
  const int swz = (xcd < r ? xcd * (q + 1) : r * (q + 1) + (xcd - r) * q) + loc;
  const int bn = (swz % gx) * 64, bm = (swz / gx) * 128;

  __shared__ __align__(16) char smem[49152];
  unsigned short* As = (unsigned short*)smem;            // [2][128*64]
  unsigned short* Bs = (unsigned short*)(smem + 32768);  // [2][64*64]
  const int tid = threadIdx.x, lane = tid & 63, w = tid >> 6;
  const int rr = lane >> 3;
  const int cc8 = (lane & 7) ^ rr;

  const int nkt = KP_ >> 6;

  auto stage = [&](int b, int kt) {
    #pragma unroll
    for (int i = 0; i < 4; ++i) {
      int R = w * 32 + i * 8;
      gl_lds16(A + (size_t)(bm + R + rr) * lda + kt * 64 + cc8 * 8,
               As + b * 8192 + R * 64);
    }
    #pragma unroll
    for (int i = 0; i < 2; ++i) {
      int R = w * 16 + i * 8;
      gl_lds16(Bt + (size_t)(bn + R + rr) * KP_ + kt * 64 + cc8 * 8,
               Bs + b * 4096 + R * 64);
    }
  };

  const int r16 = lane & 15, g4 = lane >> 4;
  f32x4 zf = {0.f, 0.f, 0.f, 0.f};
  f32x4 acc[2][4];
  #pragma unroll
  for (int m = 0; m < 2; ++m)
    #pragma unroll
    for (int n = 0; n < 4; ++n) acc[m][n] = zf;

  stage(0, 0);
  stage(1, 1);
  int buf = 0;
  for (int kt = 0; kt < nkt; ++kt) {
    if (kt == nkt - 1) asm volatile("s_waitcnt vmcnt(0)" ::: "memory");
    else               asm volatile("s_waitcnt vmcnt(6)" ::: "memory");
    __builtin_amdgcn_s_barrier();
    #pragma unroll
    for (int k2 = 0; k2 < 2; ++k2) {
      s16x8 bfr[4], afr[2];
      #pragma unroll
      for (int n = 0; n < 4; ++n) {
        int rB = n * 16 + r16;
        int ch = (k2 * 4 + g4) ^ (rB & 7);
        bfr[n] = *(const s16x8*)&Bs[buf * 4096 + rB * 64 + ch * 8];
      }
      #pragma unroll
      for (int m = 0; m < 2; ++m) {
        int rA = w * 32 + m * 16 + r16;
        int ch = (k2 * 4 + g4) ^ (rA & 7);
        afr[m] = *(const s16x8*)&As[buf * 8192 + rA * 64 + ch * 8];
      }
      __builtin_amdgcn_s_setprio(1);
      #pragma unroll
      for (int m = 0; m < 2; ++m)
        #pragma unroll
        for (int n = 0; n < 4; ++n)
          acc[m][n] = __builtin_amdgcn_mfma_f32_16x16x32_bf16(afr[m], bfr[n],
                                                              acc[m][n], 0, 0, 0);
      __builtin_amdgcn_s_setprio(0);
    }
    __builtin_amdgcn_s_barrier();
    if (kt + 2 < nkt) stage(buf, kt + 2);
    buf ^= 1;
  }

  // ---- epilogue: acc -> LDS f32 (aliases As/Bs, all reads done) ----
  float* Ct = (float*)smem;                  // [128][68]
  #pragma unroll
  for (int m = 0; m < 2; ++m) {
    int row0 = w * 32 + m * 16 + g4 * 4;
    #pragma unroll
    for (int n = 0; n < 4; ++n) {
      int col = n * 16 + r16;
      #pragma unroll
      for (int r2 = 0; r2 < 4; ++r2)
        Ct[(row0 + r2) * 68 + col] = acc[m][n][r2];
    }
  }
  __builtin_amdgcn_s_barrier();

  if (Cf) {
    for (int c = tid; c < 128 * 16; c += 256) {
      int row = c >> 4, c4 = (c & 15) * 4;
      int gm = bm + row, gn = bn + c4;
      if (gm >= M) continue;
      f32x4 v;
      #pragma unroll
      for (int rj = 0; rj < 4; ++rj) {
        float x = Ct[row * 68 + c4 + rj] + bias[gn + rj];
        if (act) x = x > 0.f ? x : 0.f;
        v[rj] = x;
      }
      *(f32x4*)(Cf + (size_t)gm * ldc + gn) = v;
    }
  } else {
    // bf16 path: output buffers are MP-row-padded and N is a multiple of 64,
    // so stores are unconditional (all 8 reduce-lanes stay active).
    for (int c = tid; c < 128 * 8; c += 256) {
      int row = c >> 3, c8 = (c & 7) * 8;
      int gm = bm + row, gn = bn + c8;
      size_t obase = (size_t)gm * ldc + gn;
      s16x8 o;
      if (Xg) {
        s16x8 xv = *(const s16x8*)(Xg + obase);
        s16x8 hv = *(const s16x8*)(Hg + obase);
        #pragma unroll
        for (int rj = 0; rj < 8; ++rj) {
          float v = Ct[row * 68 + c8 + rj] + bias[gn + rj];
          float g = 1.f / (1.f + __expf(-v));
          float x = bf2f((unsigned short)xv[rj]);
          float h = bf2f((unsigned short)hv[rj]);
          o[rj] = (short)f2bf(g * x + (1.f - g) * h);
        }
      } else {
        #pragma unroll
        for (int rj = 0; rj < 8; ++rj) {
          float v = Ct[row * 68 + c8 + rj] + bias[gn + rj];
          if (act) v = v > 0.f ? v : 0.f;
          o[rj] = (short)f2bf(v);
        }
      }
      if (wa) {
        float sj[4] = {0.f, 0.f, 0.f, 0.f};
        #pragma unroll
        for (int rj = 0; rj < 8; ++rj) {
          float vf = bf2f((unsigned short)o[rj]);
          #pragma unroll
          for (int j = 0; j < 4; ++j) sj[j] += vf * wa[j * KPA + gn + rj];
        }
        #pragma unroll
        for (int off = 1; off < 8; off <<= 1)
          #pragma unroll
          for (int j = 0; j < 4; ++j) sj[j] += __shfl_xor(sj[j], off);
        *(s16x8*)(Cb + obase) = o;
        if ((c & 7) == 0) {
          #pragma unroll
          for (int j = 0; j < 4; ++j)
            atomicAdd(&Scout[(size_t)gm * 4 + j], sj[j]);
        }
      } else {
        *(s16x8*)(Cb + obase) = o;
      }
    }
  }
}

// ============ CSR build ============
__global__ void hist_k(const int* __restrict__ ei, int* __restrict__ cnt) {
  int e = blockIdx.x * blockDim.x + threadIdx.x;
  if (e >= NETOT) return;
  int d = (e < NEDGE0) ? ei[NEDGE0 + e] : e - NEDGE0;
  atomicAdd(&cnt[d], 1);
}

__global__ __launch_bounds__(1024) void scan_k(const int* __restrict__ cnt,
                                               int* __restrict__ rowptr) {
  __shared__ int wsum[16];
  __shared__ int carry_s;
  int t = threadIdx.x, lane = t & 63, wv = t >> 6;
  if (t == 0) carry_s = 0;
  __syncthreads();
  for (int base = 0; base < NNODES; base += 1024) {
    int idx = base + t;
    int v = (idx < NNODES) ? cnt[idx] : 0;
    int s = v;
    #pragma unroll
    for (int off = 1; off < 64; off <<= 1) {
      int x = __shfl_up(s, off);
      if (lane >= off) s += x;
    }
    if (lane == 63) wsum[wv] = s;
    __syncthreads();
    if (wv == 0) {
      int ws = (lane < 16) ? wsum[lane] : 0;
      #pragma unroll
      for (int off = 1; off < 16; off <<= 1) {
        int x = __shfl_up(ws, off);
        if (lane >= off) ws += x;
      }
      if (lane < 16) wsum[lane] = ws;
    }
    __syncthreads();
    int carry = carry_s;
    int woff = wv ? wsum[wv - 1] : 0;
    if (idx < NNODES) rowptr[idx] = carry + woff + s - v;
    __syncthreads();
    if (t == 1023) carry_s = carry + wsum[15];
    __syncthreads();
  }
  if (t == 0) rowptr[NNODES] = carry_s;
}

__global__ void scatter_k(const int* __restrict__ ei, const int* __restrict__ rowptr,
                          int* __restrict__ cur, int* __restrict__ esrc) {
  int e = blockIdx.x * blockDim.x + threadIdx.x;
  if (e >= NETOT) return;
  int s, d;
  if (e < NEDGE0) { s = ei[e]; d = ei[NEDGE0 + e]; }
  else { s = d = e - NEDGE0; }
  int pos = rowptr[d] + atomicAdd(&cur[d], 1);
  esrc[pos] = s;
}

// ============ per-node scores (layer 0 only): Sc[n][4] = X[n] · wa[j] ============
template<int NCH>
__global__ __launch_bounds__(256) void scoresX_k(
    const unsigned short* __restrict__ X, int stride,
    const float* __restrict__ wa, float* __restrict__ Sc)
{
  int wid = (blockIdx.x * blockDim.x + threadIdx.x) >> 6;
  int lane = threadIdx.x & 63;
  if (wid >= NNODES) return;
  const int K = NCH * 8;
  float d[4] = {0, 0, 0, 0};
  if (lane < NCH) {
    s16x8 xv = *(const s16x8*)(X + (size_t)wid * stride + lane * 8);
    float xf[8];
    #pragma unroll
    for (int r = 0; r < 8; ++r) xf[r] = bf2f((unsigned short)xv[r]);
    #pragma unroll
    for (int j = 0; j < 4; ++j) {
      const float* wp = wa + j * K + lane * 8;
      float s = 0.f;
      #pragma unroll
      for (int r = 0; r < 8; ++r) s += xf[r] * wp[r];
      d[j] = s;
    }
  }
  #pragma unroll
  for (int off = 32; off; off >>= 1) {
    #pragma unroll
    for (int j = 0; j < 4; ++j) d[j] += __shfl_xor(d[j], off);
  }
  if (lane == 0) {
    f32x4 v = {d[0], d[1], d[2], d[3]};
    *(f32x4*)(Sc + (size_t)wid * 4) = v;
  }
}

// ============ fused edge softmax + X-aggregate (wave per node) ============
template<int NCH>
__global__ __launch_bounds__(256) void msgX_k(
    const int* __restrict__ rowptr, const int* __restrict__ esrc,
    const float* __restrict__ Sc, const unsigned short* __restrict__ X,
    int stride, unsigned short* __restrict__ xagg)
{
  int wid = (blockIdx.x * blockDim.x + threadIdx.x) >> 6;
  int lane = threadIdx.x & 63;
  if (wid >= NNODES) return;
  int e0 = rowptr[wid], e1 = rowptr[wid + 1];
  float sd0 = Sc[(size_t)wid * 4 + 2], sd1 = Sc[(size_t)wid * 4 + 3];

  // ---- phase 1: exact per-head max & sum ----
  float m0 = -1e30f, m1 = -1e30f, z0 = 0.f, z1 = 0.f;
  for (int base = e0; base < e1; base += 64) {
    int cnt = e1 - base; if (cnt > 64) cnt = 64;
    float a0 = -1e30f, a1 = -1e30f;
    if (lane < cnt) {
      int sl = esrc[base + lane];
      f32x4 sv = *(const f32x4*)(Sc + (size_t)sl * 4);
      a0 = sv[0] + sd0; a0 = a0 > 0.f ? a0 : 0.2f * a0;
      a1 = sv[1] + sd1; a1 = a1 > 0.f ? a1 : 0.2f * a1;
    }
    float cm0 = a0, cm1 = a1;
    #pragma unroll
    for (int off = 32; off; off >>= 1) {
      cm0 = fmaxf(cm0, __shfl_xor(cm0, off));
      cm1 = fmaxf(cm1, __shfl_xor(cm1, off));
    }
    float nm0 = fmaxf(m0, cm0), nm1 = fmaxf(m1, cm1);
    z0 *= __expf(m0 - nm0); z1 *= __expf(m1 - nm1);
    m0 = nm0; m1 = nm1;
    float w0 = (lane < cnt) ? __expf(a0 - m0) : 0.f;
    float w1 = (lane < cnt) ? __expf(a1 - m1) : 0.f;
    #pragma unroll
    for (int off = 32; off; off >>= 1) {
      w0 += __shfl_xor(w0, off);
      w1 += __shfl_xor(w1, off);
    }
    z0 += w0; z1 += w1;
  }
  float i0 = 1.f / (z0 + 1e-16f), i1 = 1.f / (z1 + 1e-16f);

  float a0h[8] = {0,0,0,0,0,0,0,0};
  float a1h[8] = {0,0,0,0,0,0,0,0};

  // ---- phase 2: final coefs + weighted X gather ----
  for (int base = e0; base < e1; base += 64) {
    int cnt = e1 - base; if (cnt > 64) cnt = 64;
    int sl = 0;
    float c0 = 0.f, c1 = 0.f;
    if (lane < cnt) {
      sl = esrc[base + lane];
      f32x4 sv = *(const f32x4*)(Sc + (size_t)sl * 4);
      float a0 = sv[0] + sd0; a0 = a0 > 0.f ? a0 : 0.2f * a0;
      float a1 = sv[1] + sd1; a1 = a1 > 0.f ? a1 : 0.2f * a1;
      c0 = __expf(a0 - m0) * i0;
      c1 = __expf(a1 - m1) * i1;
    }
    if (NCH == 40) {
      for (int e = 0; e < cnt; ++e) {
        int   s  = __shfl(sl, e);
        float w0 = __shfl(c0, e), w1 = __shfl(c1, e);
        if (lane < NCH) {
          s16x8 xv = *(const s16x8*)(X + (size_t)s * stride + lane * 8);
          #pragma unroll
          for (int r = 0; r < 8; ++r) {
            float xf = bf2f((unsigned short)xv[r]);
            a0h[r] += w0 * xf;
            a1h[r] += w1 * xf;
          }
        }
      }
    } else {  // NCH == 16: 4 edges per step, lane = (edge-sub << 4) | chunk
      for (int e = 0; e < cnt; e += 4) {
        int ee = e + (lane >> 4);
        bool on = ee < cnt;
        int   s  = __shfl(sl, on ? ee : e);
        float w0 = __shfl(c0, on ? ee : e), w1 = __shfl(c1, on ? ee : e);
        if (on) {
          s16x8 xv = *(const s16x8*)(X + (size_t)s * stride + (lane & 15) * 8);
          #pragma unroll
          for (int r = 0; r < 8; ++r) {
            float xf = bf2f((unsigned short)xv[r]);
            a0h[r] += w0 * xf;
            a1h[r] += w1 * xf;
          }
        }
      }
    }
  }

  if (NCH == 16) {
    #pragma unroll
    for (int r = 0; r < 8; ++r) {
      a0h[r] += __shfl_xor(a0h[r], 16); a0h[r] += __shfl_xor(a0h[r], 32);
      a1h[r] += __shfl_xor(a1h[r], 16); a1h[r] += __shfl_xor(a1h[r], 32);
    }
  }
  if (lane < NCH) {
    s16x8 o0, o1;
    #pragma unroll
    for (int r = 0; r < 8; ++r) {
      o0[r] = (short)f2bf(a0h[r]);
      o1[r] = (short)f2bf(a1h[r]);
    }
    unsigned short* op = xagg + (size_t)wid * (2 * NCH * 8);
    *(s16x8*)(op + lane * 8) = o0;
    *(s16x8*)(op + NCH * 8 + lane * 8) = o1;
  }
}

// ============ pooling ============
__global__ __launch_bounds__(256) void pool_k(const unsigned short* __restrict__ hs,
                                              const int* __restrict__ gptr,
                                              unsigned short* __restrict__ pooled) {
  int g = blockIdx.x;
  int n0 = gptr[g], n1 = gptr[g + 1];
  float inv = (n1 > n0) ? 1.f / (float)(n1 - n0) : 0.f;
  for (int c = threadIdx.x; c < KPA; c += 256) {
    float s = 0.f;
    if (c < CH)
      for (int n = n0; n < n1; ++n) s += bf2f(hs[(size_t)n * AST + c]);
    pooled[(size_t)g * KPA + c] = f2bf(s * inv);
  }
}

extern "C" void kernel_launch(void* const* d_in, const int* in_sizes, int n_in,
                              void* d_out, int out_size, void* d_ws, size_t ws_size,
                              hipStream_t stream)
{
  const float* mol_x = (const float*)d_in[0];
  const int*   ei    = (const int*)d_in[1];
  const int*   batch = (const int*)d_in[2];
  const float* W0  = (const float*)d_in[3];
  const float* as0 = (const float*)d_in[4];
  const float* ad0 = (const float*)d_in[5];
  const float* b0  = (const float*)d_in[6];
  const float* W1  = (const float*)d_in[7];
  const float* as1 = (const float*)d_in[8];
  const float* ad1 = (const float*)d_in[9];
  const float* b1  = (const float*)d_in[10];
  const float* W2  = (const float*)d_in[11];
  const float* as2 = (const float*)d_in[12];
  const float* ad2 = (const float*)d_in[13];
  const float* b2  = (const float*)d_in[14];
  const float* fc1w = (const float*)d_in[15];
  const float* fc1b = (const float*)d_in[16];
  const float* fc2w = (const float*)d_in[17];
  const float* fc2b = (const float*)d_in[18];
  const float* mbias = (const float*)d_in[19];
  const float* g1w = (const float*)d_in[20];
  const float* g1b = (const float*)d_in[21];
  const float* g2w = (const float*)d_in[22];
  const float* g2b = (const float*)d_in[23];
  float* out = (float*)d_out;

  char* ws = (char*)d_ws;
  size_t off = 0;
  auto alloc = [&](size_t b) { size_t r = off; off += (b + 255) & ~(size_t)255; return r; };
  unsigned short* xagg = (unsigned short*)(ws + alloc((size_t)MP * AST * 2));
  unsigned short* actA = (unsigned short*)(ws + alloc((size_t)MP * AST * 2));
  unsigned short* actB = (unsigned short*)(ws + alloc((size_t)MP * AST * 2));
  unsigned short* xb0  = (unsigned short*)(ws + alloc((size_t)MP * KP0 * 2));
  float* Sc     = (float*)(ws + alloc((size_t)MP * 4 * 4));
  int*   cnt    = (int*)(ws + alloc((size_t)2 * NNODES * 4));
  int*   cnt2   = cnt + NNODES;
  int*   rowptr = (int*)(ws + alloc((size_t)(NNODES + 1) * 4));
  int*   esrc   = (int*)(ws + alloc((size_t)NETOT * 4));
  int*   gptr   = (int*)(ws + alloc((size_t)(NGRAPH + 1) * 4));
  float* gbias  = (float*)(ws + alloc((size_t)KPA * 4));
  float* bp0    = (float*)(ws + alloc((size_t)KPA * 4));
  float* bp1    = (float*)(ws + alloc((size_t)KPA * 4));
  float* bp2    = (float*)(ws + alloc((size_t)KPA * 4));
  float* wa0    = (float*)(ws + alloc((size_t)4 * KP0 * 4));
  float* wa1    = (float*)(ws + alloc((size_t)4 * KPA * 4));
  float* wa2    = (float*)(ws + alloc((size_t)4 * KPA * 4));
  unsigned short* pooled_b = (unsigned short*)(ws + alloc((size_t)NGRAPH * KPA * 2));
  unsigned short* gbuf_b   = (unsigned short*)(ws + alloc((size_t)NGRAPH * GW1 * 2));
  unsigned short* comb0t = (unsigned short*)(ws + alloc((size_t)384 * 256 * 2));
  unsigned short* comb1t = (unsigned short*)(ws + alloc((size_t)384 * AST * 2));
  unsigned short* comb2t = (unsigned short*)(ws + alloc((size_t)384 * AST * 2));
  unsigned short* fc12t  = (unsigned short*)(ws + alloc((size_t)384 * AST * 2));
  unsigned short* g1t    = (unsigned short*)(ws + alloc((size_t)GW1 * KPA * 2));
  unsigned short* g2t    = (unsigned short*)(ws + alloc((size_t)128 * GW1 * 2));

  // ---- pre-pass: CSR chain + fused prep mega-kernel ----
  hipMemsetAsync(cnt, 0, (size_t)2 * NNODES * 4, stream);
  hist_k<<<(NETOT + 255) / 256, 256, 0, stream>>>(ei, cnt);
  scan_k<<<1, 1024, 0, stream>>>(cnt, rowptr);
  scatter_k<<<(NETOT + 255) / 256, 256, 0, stream>>>(ei, rowptr, cnt2, esrc);
  prep_k<<<PREPB, 256, 0, stream>>>(mol_x, xb0, W0, W1, W2, comb0t, comb1t, comb2t,
                                    as0, ad0, as1, ad1, as2, ad2, wa0, wa1, wa2,
                                    fc1w, fc2w, fc12t, b0, b1, b2, fc1b, fc2b, mbias,
                                    bp0, bp1, bp2, gbias, g1w, g1t, g2w, g2t,
                                    batch, gptr);

  auto mgemm = [&](const unsigned short* A, int lda, const unsigned short* Bt,
                   unsigned short* Cb, float* Cf, const float* bias,
                   const unsigned short* Xg, const unsigned short* Hg,
                   const float* wa, float* Scout,
                   int M, int N, int KP_, int ldc, int act) {
    int gx = (N + 63) / 64, gy = (M + 127) / 128;
    hipLaunchKernelGGL(gemm_bb, dim3(gx * gy), dim3(256), 0, stream, A, lda, Bt,
                       Cb, Cf, bias, Xg, Hg, wa, Scout, M, N, KP_, ldc, act, gx);
  };

  const int MSGB = (NNODES * 64 + 255) / 256;
  unsigned short* hA = actA + KPA;   // h-slot of actA
  unsigned short* hB = actB + KPA;   // h-slot of actB

  // ---- layer 0: scores -> aggregate X -> combined GEMM (+L1 scores) -> hA ----
  scoresX_k<16><<<MSGB, 256, 0, stream>>>(xb0, KP0, wa0, Sc);
  msgX_k<16><<<MSGB, 256, 0, stream>>>(rowptr, esrc, Sc, xb0, KP0, xagg);
  hipMemsetAsync(Sc, 0, (size_t)MP * 4 * 4, stream);
  mgemm(xagg, 256, comb0t, hA, nullptr, bp0, nullptr, nullptr, wa1, Sc,
        NNODES, KPA, 256, AST, 1);

  // ---- layer 1 ----
  msgX_k<40><<<MSGB, 256, 0, stream>>>(rowptr, esrc, Sc, hA, AST, xagg);
  mgemm(xagg, AST, comb1t, actA, nullptr, bp1, nullptr, nullptr, nullptr, nullptr,
        NNODES, KPA, AST, AST, 1);                       // x-slot of actA
  hipMemsetAsync(Sc, 0, (size_t)MP * 4 * 4, stream);
  mgemm(actA, AST, fc12t, hB, nullptr, gbias, actA, hA, wa2, Sc,
        NNODES, KPA, AST, AST, 0);                       // gate -> hB (+L2 scores)

  // ---- layer 2 ----
  msgX_k<40><<<MSGB, 256, 0, stream>>>(rowptr, esrc, Sc, hB, AST, xagg);
  mgemm(xagg, AST, comb2t, actB, nullptr, bp2, nullptr, nullptr, nullptr, nullptr,
        NNODES, KPA, AST, AST, 0);                       // x-slot of actB (no relu)
  mgemm(actB, AST, fc12t, hA, nullptr, gbias, actB, hB, nullptr, nullptr,
        NNODES, KPA, AST, AST, 0);                       // gate -> hA

  // ---- pool + head ----
  pool_k<<<NGRAPH, 256, 0, stream>>>(hA, gptr, pooled_b);
  mgemm(pooled_b, KPA, g1t, gbuf_b, nullptr, g1b, nullptr, nullptr, nullptr, nullptr,
        NGRAPH, GW1, KPA, GW1, 1);
  mgemm(gbuf_b, GW1, g2t, nullptr, out, g2b, nullptr, nullptr, nullptr, nullptr,
        NGRAPH, 128, GW1, 128, 0);
}